// Round 16
// baseline (37.675 us; speedup 1.0000x reference)
//
#include <hip/hip_runtime.h>
#include <hip/hip_bf16.h>
#include <math.h>

// B=4, T=S=512, M=N=512, H=128
#define KDIM 512
#define HDIM 128
#define SDIM 512
#define INV_SCALE 0.04419417382415922f   // 1/sqrt(512)

// score[b,t,s] = a'[b,t] + c'[b,s]  (both pre-scaled)
// ws: [0,2048) c' f32; ws[2048] = counter (zeroed by memset each launch).
// Single proj dispatch: blocks 0-127 keys->c'+publish; blocks 128-255 query proj
// (overlaps keys phase), then relaxed-spin, acquire once, fused out-write.

typedef __attribute__((ext_vector_type(8))) short bf16x8;   // 8 bf16 = 4 VGPRs
typedef __attribute__((ext_vector_type(4))) float f32x4;    // MFMA accumulator

__device__ __forceinline__ float fast_tanh(float x) {
    // tanh(x) = 1 - 2/(e^{2x}+1); ~1e-7 abs error, graceful at +/-inf
    float e = __expf(2.0f * x);
    return 1.0f - 2.0f / (e + 1.0f);
}
__device__ __forceinline__ unsigned short bfbits(float x) {
    return __builtin_bit_cast(unsigned short, __float2bfloat16(x));
}
__device__ __forceinline__ bf16x8 cvt8(const float4 p, const float4 q) {
    bf16x8 r;
    r[0] = (short)bfbits(p.x); r[1] = (short)bfbits(p.y);
    r[2] = (short)bfbits(p.z); r[3] = (short)bfbits(p.w);
    r[4] = (short)bfbits(q.x); r[5] = (short)bfbits(q.y);
    r[6] = (short)bfbits(q.z); r[7] = (short)bfbits(q.w);
    return r;
}

// r13's verified 16-row projection (512 thr, 8 waves = 8 h-tiles).
// res[r] = INV_SCALE * sum_h vv[h]*tanh(X[row0+r,:]·W[h,:]), written by tid<16.
// k-bijection: lane-group g owns k-slots {t*32+g*4..+3} u {t*32+16+g*4..+3};
// A staged bf16 in LDS (granule-swizzled by row&7), B = f32 W direct (full 64B lines).
// C layout: col = lane&15 (h), row = g*4 + reg (HW-verified r9/m89).
__device__ __forceinline__ void proj16(
    const float* __restrict__ X, const float* __restrict__ Wf,
    const float* __restrict__ vv, int row0,
    unsigned short* sm_x, float (*sm_p)[16], float* res)
{
    const int tid  = threadIdx.x;
    const int wave = tid >> 6;
    const int lane = tid & 63;

    // Stage X: wave handles rows {wave, wave+8}; granule matches the k-bijection.
    #pragma unroll
    for (int it = 0; it < 2; ++it) {
        const int row = it * 8 + wave;
        const float4* __restrict__ src = (const float4*)(X + (size_t)(row0 + row) * KDIM);
        #pragma unroll
        for (int p = 0; p < 2; ++p) {
            const int f = p * 64 + lane;          // float4 index; k = 4f..4f+3
            const float4 xv = src[f];
            ushort4 o;
            o.x = bfbits(xv.x); o.y = bfbits(xv.y);
            o.z = bfbits(xv.z); o.w = bfbits(xv.w);
            const int t    = f >> 3;              // 32-k step
            const int off4 = f & 7;
            const int g    = off4 & 3;            // k-group
            const int half = off4 >> 2;           // 0: k-off 0-15, 1: 16-31
            char* dst = (char*)sm_x + row * 1024
                      + (((t * 4 + g) ^ (row & 7)) << 4) + half * 8;
            *(ushort4*)dst = o;
        }
    }
    __syncthreads();

    const int c16 = lane & 15;
    const int g   = lane >> 4;
    const int h0  = wave * 16;
    const float* __restrict__ wrow = Wf + (size_t)(h0 + c16) * KDIM + g * 4;
    const char* __restrict__ arow = (const char*)sm_x + c16 * 1024;
    const int swz = c16 & 7;

    f32x4 acc = {0.0f, 0.0f, 0.0f, 0.0f};
    #pragma unroll 4
    for (int t = 0; t < 16; ++t) {
        const float4 b0 = *(const float4*)(wrow + t * 32);        // k t*32+g*4..+3
        const float4 b1 = *(const float4*)(wrow + t * 32 + 16);   // k t*32+16+g*4..+3
        const bf16x8 a = *(const bf16x8*)(arow + (((t * 4 + g) ^ swz) << 4));
        acc = __builtin_amdgcn_mfma_f32_16x16x32_bf16(a, cvt8(b0, b1), acc, 0, 0, 0);
    }

    const float vh = vv[h0 + c16];
    #pragma unroll
    for (int r = 0; r < 4; ++r) {
        float s = vh * fast_tanh(acc[r]);
        s += __shfl_xor(s, 1, 64);   // reduce over h-columns (lane bits 0-3)
        s += __shfl_xor(s, 2, 64);
        s += __shfl_xor(s, 4, 64);
        s += __shfl_xor(s, 8, 64);
        if (c16 == 0) sm_p[wave][g * 4 + r] = s;
    }
    __syncthreads();

    if (tid < 16) {
        float s = 0.0f;
        #pragma unroll
        for (int w = 0; w < 8; ++w) s += sm_p[w][tid];
        res[tid] = s * INV_SCALE;
    }
}

__global__ __launch_bounds__(512) void fused_kernel(
    const float* __restrict__ query, const float* __restrict__ keys,
    const float* __restrict__ W1, const float* __restrict__ W2,
    const float* __restrict__ v, float* __restrict__ ws,
    float* __restrict__ out)
{
    __shared__ __align__(16) unsigned short sm_x[16 * KDIM];  // 16 KB bf16
    __shared__ float sm_p[8][16];
    __shared__ float sm_res[16];

    const int blk = blockIdx.x;
    const int tid = threadIdx.x;
    unsigned int* ctr = (unsigned int*)(ws + 2048);

    if (blk < 128) {
        // ---- keys phase: c' rows 16*blk..+15 ----
        const int row0 = blk * 16;
        proj16(keys, W1, v + HDIM, row0, sm_x, sm_p, sm_res);
        if (tid < 16) ws[row0 + tid] = sm_res[tid];   // normal store
        __syncthreads();                               // stores issued block-wide
        if (tid == 0) {
            __threadfence();                           // flush to LLC
            __hip_atomic_fetch_add(ctr, 1u, __ATOMIC_RELEASE, __HIP_MEMORY_SCOPE_AGENT);
        }
        return;
    }

    // ---- query phase (runs concurrently with keys blocks) ----
    const int row0 = (blk - 128) * 16;
    proj16(query, W2, v, row0, sm_x, sm_p, sm_res);    // a' -> sm_res

    // Wait for all 128 keys blocks; relaxed poll by one lane only (no cache storms).
    if (tid == 0) {
        while (__hip_atomic_load(ctr, __ATOMIC_RELAXED, __HIP_MEMORY_SCOPE_AGENT) < 128u)
            __builtin_amdgcn_s_sleep(2);
    }
    __syncthreads();
    // One acquire per thread: invalidates possibly-stale L1/L2 lines of c'.
    (void)__hip_atomic_load(ctr, __ATOMIC_ACQUIRE, __HIP_MEMORY_SCOPE_AGENT);

    // Fused out-write: 16 rows x 512 cols. Thread group (tid>>7) = 4 rows; col = tid&127.
    const int b   = row0 >> 9;
    const int col = tid & 127;
    const float4 cv = ((const float4*)(ws + (size_t)b * SDIM))[col];
    const int rbase = (tid >> 7) * 4;
    #pragma unroll
    for (int rp = 0; rp < 4; ++rp) {
        const int r = rbase + rp;
        const float a = sm_res[r];
        float4 o;
        o.x = a + cv.x; o.y = a + cv.y; o.z = a + cv.z; o.w = a + cv.w;
        ((float4*)out)[(size_t)(row0 + r) * (SDIM / 4) + col] = o;
    }
}

extern "C" void kernel_launch(void* const* d_in, const int* in_sizes, int n_in,
                              void* d_out, int out_size, void* d_ws, size_t ws_size,
                              hipStream_t stream) {
    const float* query = (const float*)d_in[0];  // (4,512,512)
    const float* keys  = (const float*)d_in[1];  // (4,512,512)
    const float* W1    = (const float*)d_in[2];  // (128,512)
    const float* W2    = (const float*)d_in[3];  // (128,512)
    const float* v     = (const float*)d_in[4];  // (1,256)
    float* out = (float*)d_out;                  // (4,512,512) f32
    float* ws  = (float*)d_ws;                   // c' f32[2048] + counter

    // zero the barrier counter (capture-safe, deterministic every call)
    hipMemsetAsync((char*)d_ws + 2048 * sizeof(float), 0, 64, stream);
    fused_kernel<<<256, 512, 0, stream>>>(query, keys, W1, W2, v, ws, out);
}

// Round 17
// 16.944 us; speedup vs baseline: 2.2235x; 2.2235x over previous
//
#include <hip/hip_runtime.h>
#include <hip/hip_bf16.h>
#include <math.h>

// B=4, T=S=512, M=N=512, H=128
#define KDIM 512
#define HDIM 128
#define SDIM 512
#define TOTAL_ROWS 2048
#define INV_SCALE 0.04419417382415922f   // 1/sqrt(512)

// score[b,t,s] = a'[b,t] + c'[b,s]  (both pre-scaled)
// ws: [0,2048) a' f32; [2048,4096) c' f32.
// D1: proj both sides, 256 blocks x 512 thr, K-half software-pipelined staging.
// D2: outer broadcast-add (r13 verbatim).

typedef __attribute__((ext_vector_type(8))) short bf16x8;   // 8 bf16 = 4 VGPRs
typedef __attribute__((ext_vector_type(4))) float f32x4;    // MFMA accumulator

__device__ __forceinline__ float fast_tanh(float x) {
    // tanh(x) = 1 - 2/(e^{2x}+1); ~1e-7 abs error, graceful at +/-inf
    float e = __expf(2.0f * x);
    return 1.0f - 2.0f / (e + 1.0f);
}
__device__ __forceinline__ unsigned short bfbits(float x) {
    return __builtin_bit_cast(unsigned short, __float2bfloat16(x));
}
__device__ __forceinline__ bf16x8 cvt8(const float4 p, const float4 q) {
    bf16x8 r;
    r[0] = (short)bfbits(p.x); r[1] = (short)bfbits(p.y);
    r[2] = (short)bfbits(p.z); r[3] = (short)bfbits(p.w);
    r[4] = (short)bfbits(q.x); r[5] = (short)bfbits(q.y);
    r[6] = (short)bfbits(q.z); r[7] = (short)bfbits(q.w);
    return r;
}

// Stage one K-half of the X tile into LDS with the k-bijection granule layout.
// fhalf = thread's float4 within the half (0..1023): row = fhalf>>6, fr = fhalf&63,
// global k-step s = fr>>3 + 8*halfsel. Swizzle: granule (s*4+g) ^ (row&7) stays
// within the half's granule range (A: 0..31, B: 32..63) since XOR flips bits 0-2.
__device__ __forceinline__ void stage_half(
    unsigned short* sm_x, const float4 xv, int fhalf, int halfsel)
{
    const int row  = fhalf >> 6;
    const int fr   = fhalf & 63;
    const int s    = (fr >> 3) + halfsel * 8;   // global 32-k step
    const int off4 = fr & 7;
    const int g    = off4 & 3;
    const int half = off4 >> 2;
    ushort4 o;
    o.x = bfbits(xv.x); o.y = bfbits(xv.y);
    o.z = bfbits(xv.z); o.w = bfbits(xv.w);
    char* dst = (char*)sm_x + row * 1024 + (((s * 4 + g) ^ (row & 7)) << 4) + half * 8;
    *(ushort4*)dst = o;
}

// 256 blocks x 512 thr (8 waves): blk<128 query w/ W2 -> ws[0:2048);
// blk>=128 keys w/ W1 -> ws[2048:4096). 16 rows/block; wave = h-tile h0=16*wave.
// K-half pipelined: stage k[0,256) -> sync -> issue k[256,512) loads ->
// MFMA steps 0-7 (hides the in-flight loads) -> write+sync -> MFMA steps 8-15.
// k-bijection (r11/r13-verified); B = f32 W direct (full 64B lines).
// C layout: col = lane&15 (h), row = g*4 + reg  ->  acc[r] = X[row0+g*4+r]·W[h0+c16].
__global__ __launch_bounds__(512) void proj_kernel(
    const float* __restrict__ query, const float* __restrict__ keys,
    const float* __restrict__ W1, const float* __restrict__ W2,
    const float* __restrict__ v, float* __restrict__ ws)
{
    const int blk = blockIdx.x;
    const bool is_keys = (blk >= 128);
    const float* __restrict__ X  = is_keys ? keys : query;
    const float* __restrict__ Wf = is_keys ? W1 : W2;
    const float* __restrict__ vv = v + (is_keys ? HDIM : 0);
    float* __restrict__ out = ws + (is_keys ? TOTAL_ROWS : 0);
    const int row0 = (blk & 127) * 16;

    __shared__ __align__(16) unsigned short sm_x[16 * KDIM];  // 16 KB bf16
    __shared__ float sm_p[8][16];

    const int tid  = threadIdx.x;
    const int wave = tid >> 6;
    const int lane = tid & 63;

    const float4* __restrict__ xsrc = (const float4*)(X + (size_t)row0 * KDIM);

    // ---- Phase A stage: k in [0,256) for all 16 rows (1024 float4, 2/thread). ----
    // Thread's float4 within a half: fhalf = tid + i*512; row = fhalf>>6 (wave-contig).
    {
        const int f0 = tid, f1 = tid + 512;
        const float4 xa0 = xsrc[(f0 >> 6) * 128 + (f0 & 63)];
        const float4 xa1 = xsrc[(f1 >> 6) * 128 + (f1 & 63)];
        stage_half(sm_x, xa0, f0, 0);
        stage_half(sm_x, xa1, f1, 0);
    }
    __syncthreads();

    // ---- Issue Phase B loads NOW (k in [256,512)); consumed after loop A. ----
    const int f0 = tid, f1 = tid + 512;
    const float4 xb0 = xsrc[(f0 >> 6) * 128 + 64 + (f0 & 63)];
    const float4 xb1 = xsrc[(f1 >> 6) * 128 + 64 + (f1 & 63)];

    const int c16 = lane & 15;
    const int g   = lane >> 4;
    const int h0  = wave * 16;
    const float* __restrict__ wrow = Wf + (size_t)(h0 + c16) * KDIM + g * 4;
    const char* __restrict__ arow = (const char*)sm_x + c16 * 1024;
    const int swz = c16 & 7;

    f32x4 acc = {0.0f, 0.0f, 0.0f, 0.0f};

    // ---- Loop A: K-steps 0-7 (k 0-255) — covers the Phase B loads in flight. ----
    #pragma unroll
    for (int t = 0; t < 8; ++t) {
        const float4 b0 = *(const float4*)(wrow + t * 32);        // k t*32+g*4..+3
        const float4 b1 = *(const float4*)(wrow + t * 32 + 16);   // k t*32+16+g*4..+3
        const bf16x8 a = *(const bf16x8*)(arow + (((t * 4 + g) ^ swz) << 4));
        acc = __builtin_amdgcn_mfma_f32_16x16x32_bf16(a, cvt8(b0, b1), acc, 0, 0, 0);
    }

    // ---- Phase B stage (disjoint LDS region; one sync before reads). ----
    stage_half(sm_x, xb0, f0, 1);
    stage_half(sm_x, xb1, f1, 1);
    __syncthreads();

    // ---- Loop B: K-steps 8-15 (k 256-511). ----
    #pragma unroll
    for (int t = 8; t < 16; ++t) {
        const float4 b0 = *(const float4*)(wrow + t * 32);
        const float4 b1 = *(const float4*)(wrow + t * 32 + 16);
        const bf16x8 a = *(const bf16x8*)(arow + (((t * 4 + g) ^ swz) << 4));
        acc = __builtin_amdgcn_mfma_f32_16x16x32_bf16(a, cvt8(b0, b1), acc, 0, 0, 0);
    }

    // acc[r] = dot(X[row0+g*4+r], W[h0+c16]); weight by v, tanh, reduce over h.
    const float vh = vv[h0 + c16];
    #pragma unroll
    for (int r = 0; r < 4; ++r) {
        float s = vh * fast_tanh(acc[r]);
        s += __shfl_xor(s, 1, 64);   // reduce over h-columns (lane bits 0-3)
        s += __shfl_xor(s, 2, 64);
        s += __shfl_xor(s, 4, 64);
        s += __shfl_xor(s, 8, 64);
        if (c16 == 0) sm_p[wave][g * 4 + r] = s;
    }
    __syncthreads();

    if (tid < 16) {
        float s = 0.0f;
        #pragma unroll
        for (int w = 0; w < 8; ++w) s += sm_p[w][tid];
        out[row0 + tid] = s * INV_SCALE;
    }
}

// 256 blocks x 256 thr; block = 8 bt-rows (single batch each). c' row stays L1-hot.
__global__ __launch_bounds__(256) void outer_kernel(
    const float* __restrict__ ws, float* __restrict__ out)
{
    const int r0  = blockIdx.x * 8;
    const int b   = r0 >> 9;
    const float4* __restrict__ c4 = (const float4*)(ws + TOTAL_ROWS + (size_t)b * SDIM);
    const int col = threadIdx.x & 127;
    const int rh  = threadIdx.x >> 7;   // 0/1

    #pragma unroll
    for (int rp = 0; rp < 4; ++rp) {
        const int row = r0 + rp * 2 + rh;
        const float a = ws[row];
        const float4 c = c4[col];
        float4 o;
        o.x = a + c.x; o.y = a + c.y; o.z = a + c.z; o.w = a + c.w;
        ((float4*)out)[(size_t)row * (SDIM / 4) + col] = o;
    }
}

extern "C" void kernel_launch(void* const* d_in, const int* in_sizes, int n_in,
                              void* d_out, int out_size, void* d_ws, size_t ws_size,
                              hipStream_t stream) {
    const float* query = (const float*)d_in[0];  // (4,512,512)
    const float* keys  = (const float*)d_in[1];  // (4,512,512)
    const float* W1    = (const float*)d_in[2];  // (128,512)
    const float* W2    = (const float*)d_in[3];  // (128,512)
    const float* v     = (const float*)d_in[4];  // (1,256)
    float* out = (float*)d_out;                  // (4,512,512) f32
    float* ws  = (float*)d_ws;                   // a' + c' (4096 floats)

    proj_kernel<<<256, 512, 0, stream>>>(query, keys, W1, W2, v, ws);
    outer_kernel<<<256, 256, 0, stream>>>(ws, out);
}